// Round 13
// baseline (274.005 us; speedup 1.0000x reference)
//
#include <hip/hip_runtime.h>
#include <hip/hip_bf16.h>

typedef __bf16 bf16;
typedef __attribute__((ext_vector_type(8))) __bf16 bf16x8;
typedef __attribute__((ext_vector_type(4))) __bf16 bf16x4;
typedef __attribute__((ext_vector_type(4))) float f32x4;

// Problem constants
#define BB 2
#define SS 2048
#define HH 2048
#define NH 16
#define HD 128

#define GLOAD_LDS16(g, l)                                                  \
    __builtin_amdgcn_global_load_lds(                                      \
        (const __attribute__((address_space(1))) void*)(g),                \
        (__attribute__((address_space(3))) void*)(l), 16, 0, 0)

// ---------------------------------------------------------------------------
// Batched fp32 -> bf16 cast: X then Wq,Wk,Wv (into contiguous Wqkv), Wo.
// ---------------------------------------------------------------------------
__global__ __launch_bounds__(256) void cast_all(const float* __restrict__ hs,
                                                const float* __restrict__ Wq,
                                                const float* __restrict__ Wk,
                                                const float* __restrict__ Wv,
                                                const float* __restrict__ Wo,
                                                bf16* __restrict__ Xb,
                                                bf16* __restrict__ Wqkv,
                                                bf16* __restrict__ Wob) {
    const int XE4 = (BB * SS * HH) / 4;
    const int WE4 = (HH * HH) / 4;
    int i = blockIdx.x * 256 + threadIdx.x;
    const float* src;
    bf16* dst;
    int off;
    if (i < XE4) { src = hs; dst = Xb; off = i; }
    else if (i < XE4 + WE4) { src = Wq; dst = Wqkv; off = i - XE4; }
    else if (i < XE4 + 2 * WE4) { src = Wk; dst = Wqkv + (size_t)HH * HH; off = i - XE4 - WE4; }
    else if (i < XE4 + 3 * WE4) { src = Wv; dst = Wqkv + 2 * (size_t)HH * HH; off = i - XE4 - 2 * WE4; }
    else { src = Wo; dst = Wob; off = i - XE4 - 3 * WE4; }
    f32x4 v = *reinterpret_cast<const f32x4*>(src + (size_t)off * 4);
    bf16x4 o;
    o[0] = (bf16)v[0]; o[1] = (bf16)v[1]; o[2] = (bf16)v[2]; o[3] = (bf16)v[3];
    *reinterpret_cast<bf16x4*>(dst + (size_t)off * 4) = o;
}

// ---------------------------------------------------------------------------
// 256x192-tile 3-phase GEMM, QKV epilogue (R12 version, 120 us).
// ---------------------------------------------------------------------------
__global__ __launch_bounds__(512, 2) void gemm256_qkv(const bf16* __restrict__ A,
                                                      const bf16* __restrict__ B,
                                                      bf16* __restrict__ Cb,
                                                      int M, int N, int K) {
    __shared__ bf16 LA[2][256 * 64];
    __shared__ bf16 LB[2][192 * 64];
    const int tid = threadIdx.x, lane = tid & 63, wave = tid >> 6;
    const int l15 = lane & 15, lhi = lane >> 4;
    const int wr = wave >> 2, wc = wave & 3;
    const int cpx = gridDim.x >> 3;
    const int wg = (blockIdx.x & 7) * cpx + (blockIdx.x >> 3);
    const int m0 = (wg & 15) * 256, n0 = (wg >> 4) * 192;
    const int NK = K >> 6;
    const int xorR = (l15 & 7) << 4;

    auto stageA = [&](int buf, int t, int h) {
        const int k0 = t << 6;
#pragma unroll
        for (int j = 0; j < 2; ++j) {
            int Xw = (h * 128 + j * 64 + wave * 8) << 7;
            int X = Xw + lane * 16;
            int T = X ^ (((X >> 7) & 7) << 4);
            GLOAD_LDS16(&A[(size_t)(m0 + (T >> 7)) * K + k0 + ((T & 127) >> 1)],
                        (char*)LA[buf] + Xw);
        }
    };
    auto stageB = [&](int buf, int t, int s) {
        const int k0 = t << 6;
        int row_base = (wave >> 1) * 48 + s * 16 + (wave & 1) * 8;
        int Xw = row_base << 7;
        int X = Xw + lane * 16;
        int T = X ^ (((X >> 7) & 7) << 4);
        GLOAD_LDS16(&B[(size_t)(n0 + (T >> 7)) * K + k0 + ((T & 127) >> 1)],
                    (char*)LB[buf] + Xw);
    };

    f32x4 acc[8][3] = {};

    stageA(0, 0, 0); stageA(0, 0, 1);
    stageB(0, 0, 0); stageB(0, 0, 1); stageB(0, 0, 2);
    stageA(1, 1, 0); stageA(1, 1, 1);
    stageB(1, 1, 0); stageB(1, 1, 1);
    asm volatile("s_waitcnt vmcnt(6)" ::: "memory");
    __builtin_amdgcn_s_barrier();

    bf16x8 af[8][2], bv[2];

#pragma unroll 1
    for (int t = 0; t < NK; ++t) {
        const int buf = t & 1;
        char* lA = (char*)LA[buf];
        char* lB = (char*)LB[buf];

        // p0
#pragma unroll
        for (int mf = 0; mf < 8; ++mf)
#pragma unroll
            for (int ks = 0; ks < 2; ++ks) {
                int T = ((wr * 128 + mf * 16 + l15) << 7) + ks * 64 + lhi * 16;
                af[mf][ks] = *reinterpret_cast<const bf16x8*>(lA + (T ^ xorR));
            }
#pragma unroll
        for (int ks = 0; ks < 2; ++ks) {
            int T = ((wc * 48 + l15) << 7) + ks * 64 + lhi * 16;
            bv[ks] = *reinterpret_cast<const bf16x8*>(lB + (T ^ xorR));
        }
        if (t + 1 < NK) stageB(buf ^ 1, t + 1, 2);
        __builtin_amdgcn_s_barrier();
        __builtin_amdgcn_s_setprio(1);
#pragma unroll
        for (int mf = 0; mf < 8; ++mf)
#pragma unroll
            for (int ks = 0; ks < 2; ++ks)
                acc[mf][0] = __builtin_amdgcn_mfma_f32_16x16x32_bf16(af[mf][ks], bv[ks], acc[mf][0], 0, 0, 0);
        __builtin_amdgcn_s_setprio(0);
        __builtin_amdgcn_s_barrier();

        // p1
#pragma unroll
        for (int ks = 0; ks < 2; ++ks) {
            int T = ((wc * 48 + 16 + l15) << 7) + ks * 64 + lhi * 16;
            bv[ks] = *reinterpret_cast<const bf16x8*>(lB + (T ^ xorR));
        }
        if (t + 2 < NK) { stageB(buf, t + 2, 0); stageA(buf, t + 2, 0); }
        __builtin_amdgcn_s_barrier();
        __builtin_amdgcn_s_setprio(1);
#pragma unroll
        for (int mf = 0; mf < 8; ++mf)
#pragma unroll
            for (int ks = 0; ks < 2; ++ks)
                acc[mf][1] = __builtin_amdgcn_mfma_f32_16x16x32_bf16(af[mf][ks], bv[ks], acc[mf][1], 0, 0, 0);
        __builtin_amdgcn_s_setprio(0);
        __builtin_amdgcn_s_barrier();

        // p2
#pragma unroll
        for (int ks = 0; ks < 2; ++ks) {
            int T = ((wc * 48 + 32 + l15) << 7) + ks * 64 + lhi * 16;
            bv[ks] = *reinterpret_cast<const bf16x8*>(lB + (T ^ xorR));
        }
        if (t + 2 < NK) { stageB(buf, t + 2, 1); stageA(buf, t + 2, 1); }
        __builtin_amdgcn_s_barrier();
        __builtin_amdgcn_s_setprio(1);
#pragma unroll
        for (int mf = 0; mf < 8; ++mf)
#pragma unroll
            for (int ks = 0; ks < 2; ++ks)
                acc[mf][2] = __builtin_amdgcn_mfma_f32_16x16x32_bf16(af[mf][ks], bv[ks], acc[mf][2], 0, 0, 0);
        __builtin_amdgcn_s_setprio(0);
        if (t + 2 < NK) {
            asm volatile("s_waitcnt vmcnt(6)" ::: "memory");
        } else if (t + 2 == NK) {
            asm volatile("s_waitcnt vmcnt(0)" ::: "memory");
        }
        __builtin_amdgcn_s_barrier();
    }

#pragma unroll
    for (int mf = 0; mf < 8; ++mf)
#pragma unroll
        for (int nsl = 0; nsl < 3; ++nsl)
#pragma unroll
            for (int r = 0; r < 4; ++r) {
                int gm = m0 + wr * 128 + mf * 16 + lhi * 4 + r;
                int gn = n0 + wc * 48 + nsl * 16 + l15;
                int proj = gn >> 11, n2 = gn & 2047;
                int b = gm >> 11, s = gm & (SS - 1);
                int h = n2 >> 7, d = n2 & (HD - 1);
                Cb[((size_t)proj << 23) + ((((size_t)(b * NH + h)) * SS + s) << 7) + d] =
                    (bf16)acc[mf][nsl][r];
            }
}

// ---------------------------------------------------------------------------
// Out-projection: 256x128-tile 2-phase GEMM, fp32 epilogue.
// Grid 16m x 16n = 256 blocks = exactly 1 round. 8 waves (2x4); per-wave
// 128x32 = acc[8][2]. Staging: p0->Bs1(t+1), p1->Bs0+A0+A1(t+2);
// boundary vmcnt(5). n-major XCD chunks (2 n-cols/XCD -> B ws 1MB, L2-fit).
// ---------------------------------------------------------------------------
__global__ __launch_bounds__(512, 2) void gemm_op(const bf16* __restrict__ A,
                                                  const bf16* __restrict__ B,
                                                  float* __restrict__ Cf,
                                                  int M, int N, int K) {
    __shared__ bf16 LA[2][256 * 64];   // 64 KiB
    __shared__ bf16 LB[2][128 * 64];   // 32 KiB
    const int tid = threadIdx.x, lane = tid & 63, wave = tid >> 6;
    const int l15 = lane & 15, lhi = lane >> 4;
    const int wr = wave >> 2, wc = wave & 3;
    const int cpx = gridDim.x >> 3;                        // 32
    const int wg = (blockIdx.x & 7) * cpx + (blockIdx.x >> 3);
    const int m0 = (wg & 15) * 256, n0 = (wg >> 4) * 128;  // n-major chunks
    const int NK = K >> 6;
    const int xorR = (l15 & 7) << 4;

    auto stageA = [&](int buf, int t, int h) {
        const int k0 = t << 6;
#pragma unroll
        for (int j = 0; j < 2; ++j) {
            int Xw = (h * 128 + j * 64 + wave * 8) << 7;
            int X = Xw + lane * 16;
            int T = X ^ (((X >> 7) & 7) << 4);
            GLOAD_LDS16(&A[(size_t)(m0 + (T >> 7)) * K + k0 + ((T & 127) >> 1)],
                        (char*)LA[buf] + Xw);
        }
    };
    // stage B slice s: rows {wc'*32 + s*16 .. +15}, 1 load/thread
    auto stageB = [&](int buf, int t, int s) {
        const int k0 = t << 6;
        int row_base = (wave >> 1) * 32 + s * 16 + (wave & 1) * 8;
        int Xw = row_base << 7;
        int X = Xw + lane * 16;
        int T = X ^ (((X >> 7) & 7) << 4);
        GLOAD_LDS16(&B[(size_t)(n0 + (T >> 7)) * K + k0 + ((T & 127) >> 1)],
                    (char*)LB[buf] + Xw);
    };

    f32x4 acc[8][2] = {};

    // prologue: t0 full (6), t1 minus Bs1 (5); wait t0
    stageA(0, 0, 0); stageA(0, 0, 1); stageB(0, 0, 0); stageB(0, 0, 1);
    stageA(1, 1, 0); stageA(1, 1, 1); stageB(1, 1, 0);
    asm volatile("s_waitcnt vmcnt(5)" ::: "memory");
    __builtin_amdgcn_s_barrier();

    bf16x8 af[8][2], bv[2];

#pragma unroll 1
    for (int t = 0; t < NK; ++t) {
        const int buf = t & 1;
        char* lA = (char*)LA[buf];
        char* lB = (char*)LB[buf];

        // p0: af(16) + bv s0(2); stage Bs1(t+1)
#pragma unroll
        for (int mf = 0; mf < 8; ++mf)
#pragma unroll
            for (int ks = 0; ks < 2; ++ks) {
                int T = ((wr * 128 + mf * 16 + l15) << 7) + ks * 64 + lhi * 16;
                af[mf][ks] = *reinterpret_cast<const bf16x8*>(lA + (T ^ xorR));
            }
#pragma unroll
        for (int ks = 0; ks < 2; ++ks) {
            int T = ((wc * 32 + l15) << 7) + ks * 64 + lhi * 16;
            bv[ks] = *reinterpret_cast<const bf16x8*>(lB + (T ^ xorR));
        }
        if (t + 1 < NK) stageB(buf ^ 1, t + 1, 1);
        __builtin_amdgcn_s_barrier();
        __builtin_amdgcn_s_setprio(1);
#pragma unroll
        for (int mf = 0; mf < 8; ++mf)
#pragma unroll
            for (int ks = 0; ks < 2; ++ks)
                acc[mf][0] = __builtin_amdgcn_mfma_f32_16x16x32_bf16(af[mf][ks], bv[ks], acc[mf][0], 0, 0, 0);
        __builtin_amdgcn_s_setprio(0);
        __builtin_amdgcn_s_barrier();

        // p1: bv s1(2); stage Bs0+A0+A1(t+2); boundary vmcnt(5)
#pragma unroll
        for (int ks = 0; ks < 2; ++ks) {
            int T = ((wc * 32 + 16 + l15) << 7) + ks * 64 + lhi * 16;
            bv[ks] = *reinterpret_cast<const bf16x8*>(lB + (T ^ xorR));
        }
        if (t + 2 < NK) { stageB(buf, t + 2, 0); stageA(buf, t + 2, 0); stageA(buf, t + 2, 1); }
        __builtin_amdgcn_s_barrier();
        __builtin_amdgcn_s_setprio(1);
#pragma unroll
        for (int mf = 0; mf < 8; ++mf)
#pragma unroll
            for (int ks = 0; ks < 2; ++ks)
                acc[mf][1] = __builtin_amdgcn_mfma_f32_16x16x32_bf16(af[mf][ks], bv[ks], acc[mf][1], 0, 0, 0);
        __builtin_amdgcn_s_setprio(0);
        if (t + 2 < NK) {
            asm volatile("s_waitcnt vmcnt(5)" ::: "memory");
        } else {
            asm volatile("s_waitcnt vmcnt(0)" ::: "memory");
        }
        __builtin_amdgcn_s_barrier();
    }

#pragma unroll
    for (int mf = 0; mf < 8; ++mf)
#pragma unroll
        for (int nsl = 0; nsl < 2; ++nsl)
#pragma unroll
            for (int r = 0; r < 4; ++r) {
                int gm = m0 + wr * 128 + mf * 16 + lhi * 4 + r;
                int gn = n0 + wc * 32 + nsl * 16 + l15;
                Cf[(size_t)gm * N + gn] = acc[mf][nsl][r];
            }
}

// ---------------------------------------------------------------------------
// Merged RoPE + V-transpose (one launch, two block ranges).
// ---------------------------------------------------------------------------
__global__ __launch_bounds__(256) void rope_tv(bf16* __restrict__ Qh,
                                               bf16* __restrict__ Kh,
                                               const float* __restrict__ cosT,
                                               const float* __restrict__ sinT,
                                               const bf16* __restrict__ Vh,
                                               bf16* __restrict__ Vt) {
    __shared__ bf16 T[64 * 64];
    const int tid = threadIdx.x;
    if (blockIdx.x < 2048) {
        int idx = blockIdx.x * 256 + tid;
        int g = idx & 7;
        int s = (idx >> 3) & (SS - 1);
        int head = idx >> 14;
        int d0 = g * 8;
        size_t base = ((size_t)head * SS + s) * HD;
        f32x4 ca = *reinterpret_cast<const f32x4*>(&cosT[s * HD + d0]);
        f32x4 cb = *reinterpret_cast<const f32x4*>(&cosT[s * HD + d0 + 4]);
        f32x4 sa = *reinterpret_cast<const f32x4*>(&sinT[s * HD + d0]);
        f32x4 sb = *reinterpret_cast<const f32x4*>(&sinT[s * HD + d0 + 4]);
        bf16x8 ql = *reinterpret_cast<const bf16x8*>(&Qh[base + d0]);
        bf16x8 qh = *reinterpret_cast<const bf16x8*>(&Qh[base + 64 + d0]);
        bf16x8 kl = *reinterpret_cast<const bf16x8*>(&Kh[base + d0]);
        bf16x8 kh = *reinterpret_cast<const bf16x8*>(&Kh[base + 64 + d0]);
        bf16x8 qlo, qhi, klo, khi;
#pragma unroll
        for (int j = 0; j < 8; ++j) {
            float c = (j < 4) ? ca[j] : cb[j - 4];
            float sn = (j < 4) ? sa[j] : sb[j - 4];
            float q0 = (float)ql[j], q1 = (float)qh[j];
            float k0 = (float)kl[j], k1 = (float)kh[j];
            qlo[j] = (bf16)(q0 * c - q1 * sn);
            qhi[j] = (bf16)(q1 * c + q0 * sn);
            klo[j] = (bf16)(k0 * c - k1 * sn);
            khi[j] = (bf16)(k1 * c + k0 * sn);
        }
        *reinterpret_cast<bf16x8*>(&Qh[base + d0]) = qlo;
        *reinterpret_cast<bf16x8*>(&Qh[base + 64 + d0]) = qhi;
        *reinterpret_cast<bf16x8*>(&Kh[base + d0]) = klo;
        *reinterpret_cast<bf16x8*>(&Kh[base + 64 + d0]) = khi;
    } else {
        const int b2 = blockIdx.x - 2048;
        const int s0 = (b2 & 31) * 64;
        const int d0 = ((b2 >> 5) & 1) * 64;
        const int head = b2 >> 6;
        const bf16* src = Vh + ((size_t)head * SS) * HD;
        bf16* dst = Vt + ((size_t)head * HD) * SS;

#pragma unroll
        for (int i = 0; i < 2; ++i) {
            int id = tid + i * 256;
            int r = id >> 3, c16 = id & 7;
            bf16x8 v = *reinterpret_cast<const bf16x8*>(&src[(size_t)(s0 + r) * HD + d0 + c16 * 8]);
            int sw = c16 ^ ((r ^ (r >> 3)) & 7);
            *reinterpret_cast<bf16x8*>((char*)T + r * 128 + sw * 16) = v;
        }
        __syncthreads();
#pragma unroll
        for (int i = 0; i < 2; ++i) {
            int id = tid + i * 256;
            int dr = id >> 3, sc8 = (id & 7) * 8;
            bf16x8 o;
#pragma unroll
            for (int j = 0; j < 8; ++j) {
                int r = sc8 + j;
                int sw = (dr >> 3) ^ ((r ^ (r >> 3)) & 7);
                o[j] = *reinterpret_cast<const bf16*>((char*)T + r * 128 + sw * 16 + (dr & 7) * 2);
            }
            *reinterpret_cast<bf16x8*>(&dst[(size_t)(d0 + dr) * SS + s0 + sc8]) = o;
        }
    }
}

// ---------------------------------------------------------------------------
// Causal flash attention v2: 4 waves x 32 q-rows (2 m-frags/wave), QB=128,
// KVBLK=64. Each kf/vb LDS read is shared by both m-frags -> per-MFMA LDS
// traffic ~halved vs 8x16 (attn was LDS-port-bound: 8 waves x 34 b128 x 12cy
// ~= the measured 4900 cy/iter). K/V dbuf via global_load_lds, one barrier
// per iter. Grid 256 = 32 heads x 8 uniform pairs (T, 15-T), 34 iters each.
// ---------------------------------------------------------------------------
__global__ __launch_bounds__(256) void attn_kernel(const bf16* __restrict__ Q,
                                                   const bf16* __restrict__ K,
                                                   const bf16* __restrict__ Vt,
                                                   bf16* __restrict__ Ob) {
    __shared__ bf16 Ks[2][64 * 128];   // 32 KiB
    __shared__ bf16 Vs[2][128 * 64];   // 32 KiB
    __shared__ bf16 Ps[4][32 * 72];    // 18 KiB

    const int tid = threadIdx.x, lane = tid & 63, wave = tid >> 6;  // wave 0..3
    const int l15 = lane & 15, lhi = lane >> 4;
    const int bid = blockIdx.x;
    const int orig = (bid & 7) * 32 + (bid >> 3);   // XCD swizzle (256 % 8 == 0)
    const int head = orig >> 3;
    const int pi = orig & 7;
    const int b = head >> 4, h = head & (NH - 1);
    const size_t hb = (size_t)head * SS * HD;
    const bf16* Vth = Vt + (size_t)head * HD * SS;
    const float cexp = 0.08838834764831845f * 1.4426950408889634f;
    const float THR = 62.0f;

    // stage K+V tile (8 gload_lds per thread, 256 threads)
    auto stageKV = [&](int buf, int kv0) {
#pragma unroll
        for (int j = 0; j < 4; ++j) {
            int Xw = (j * 4 + wave) << 10;
            int X = Xw + lane * 16;
            int T = X ^ (((X >> 8) & 7) << 4);     // K: row bits at 8+
            GLOAD_LDS16(&K[hb + (size_t)(kv0 + (T >> 8)) * HD + ((T & 255) >> 1)],
                        (char*)Ks[buf] + Xw);
        }
#pragma unroll
        for (int j = 0; j < 4; ++j) {
            int Xw = (j * 4 + wave) << 10;
            int X = Xw + lane * 16;
            int T = X ^ (((X >> 7) & 7) << 4);     // V: row bits at 7+
            GLOAD_LDS16(&Vth[(size_t)(T >> 7) * SS + kv0 + ((T & 127) >> 1)],
                        (char*)Vs[buf] + Xw);
        }
    };

#pragma unroll 1
    for (int part = 0; part < 2; ++part) {
        const int t = part ? (15 - pi) : pi;
        const int q0 = t * 128;
        const int qw0 = q0 + wave * 32;
        const int nkv = 2 * t + 2;

        bf16x8 qf[2][4];
#pragma unroll
        for (int mf = 0; mf < 2; ++mf)
#pragma unroll
            for (int ks = 0; ks < 4; ++ks)
                qf[mf][ks] = *reinterpret_cast<const bf16x8*>(
                    &Q[hb + (size_t)(qw0 + mf * 16 + l15) * HD + ks * 32 + 8 * lhi]);

        f32x4 oacc[2][8] = {};
        float Mr[2][4], Lp[2][4];
#pragma unroll
        for (int mf = 0; mf < 2; ++mf)
#pragma unroll
            for (int r = 0; r < 4; ++r) { Mr[mf][r] = -INFINITY; Lp[mf][r] = 0.f; }

        stageKV(0, 0);
        asm volatile("s_waitcnt vmcnt(0)" ::: "memory");
        __builtin_amdgcn_s_barrier();

        for (int it = 0; it < nkv; ++it) {
            const int cur = it & 1;
            if (it + 1 < nkv) stageKV(cur ^ 1, (it + 1) * 64);

            // ---- S = Q K^T: each kf read shared across both m-frags ----
            f32x4 sf[2][4] = {};
#pragma unroll
            for (int ks = 0; ks < 4; ++ks) {
#pragma unroll
                for (int ne = 0; ne < 4; ++ne) {
                    int row = ne * 16 + l15;
                    bf16x8 kf = *reinterpret_cast<const bf16x8*>(
                        (const char*)Ks[cur] + ((row * 256 + (ks * 4 + lhi) * 16) ^ ((row & 7) << 4)));
#pragma unroll
                    for (int mf = 0; mf < 2; ++mf)
                        sf[mf][ne] = __builtin_amdgcn_mfma_f32_16x16x32_bf16(qf[mf][ks], kf, sf[mf][ne], 0, 0, 0);
                }
            }

            // causal mask: last two kv-tiles intersect the diagonal band
            if (it >= nkv - 2) {
#pragma unroll
                for (int mf = 0; mf < 2; ++mf)
#pragma unroll
                    for (int ne = 0; ne < 4; ++ne)
#pragma unroll
                        for (int r = 0; r < 4; ++r) {
                            int gq = qw0 + mf * 16 + lhi * 4 + r;
                            int gk = it * 64 + ne * 16 + l15;
                            if (gk > gq) sf[mf][ne][r] = -INFINITY;
                        }
            }

            // ---- defer-max online softmax (per m-frag state) ----
            float lm[2][4];
            bool need = false;
#pragma unroll
            for (int mf = 0; mf < 2; ++mf)
#pragma unroll
                for (int r = 0; r < 4; ++r) {
                    lm[mf][r] = fmaxf(fmaxf(sf[mf][0][r], sf[mf][1][r]),
                                      fmaxf(sf[mf][2][r], sf[mf][3][r]));
                    need = need || (lm[mf][r] > Mr[mf][r] + THR);
                }
            if (__any(need)) {
                float rmax[2][4];
#pragma unroll
                for (int mf = 0; mf < 2; ++mf)
#pragma unroll
                    for (int r = 0; r < 4; ++r) rmax[mf][r] = lm[mf][r];
#pragma unroll
                for (int m = 1; m < 16; m <<= 1)
#pragma unroll
                    for (int mf = 0; mf < 2; ++mf)
#pragma unroll
                        for (int r = 0; r < 4; ++r)
                            rmax[mf][r] = fmaxf(rmax[mf][r], __shfl_xor(rmax[mf][r], m));
#pragma unroll
                for (int mf = 0; mf < 2; ++mf)
#pragma unroll
                    for (int r = 0; r < 4; ++r) {
                        float nM = fmaxf(Mr[mf][r], rmax[mf][r]);
                        float scf = __builtin_amdgcn_exp2f((Mr[mf][r] - nM) * cexp);
                        Mr[mf][r] = nM;
                        Lp[mf][r] *= scf;
#pragma unroll
                        for (int nf = 0; nf < 8; ++nf) oacc[mf][nf][r] *= scf;
                    }
            }
#pragma unroll
            for (int mf = 0; mf < 2; ++mf)
#pragma unroll
                for (int ne = 0; ne < 4; ++ne)
#pragma unroll
                    for (int r = 0; r < 4; ++r) {
                        float p = __builtin_amdgcn_exp2f((sf[mf][ne][r] - Mr[mf][r]) * cexp);
                        Lp[mf][r] += p;
                        Ps[wave][(mf * 16 + lhi * 4 + r) * 72 + ne * 16 + l15] = (bf16)p;
                    }

            // ---- O += P @ V: each vb read shared across both m-frags ----
#pragma unroll
            for (int ks = 0; ks < 2; ++ks) {
                bf16x8 pa0 = *reinterpret_cast<const bf16x8*>(
                    &Ps[wave][(l15) * 72 + ks * 32 + 8 * lhi]);
                bf16x8 pa1 = *reinterpret_cast<const bf16x8*>(
                    &Ps[wave][(16 + l15) * 72 + ks * 32 + 8 * lhi]);
#pragma unroll
                for (int nf = 0; nf < 8; ++nf) {
                    int row = nf * 16 + l15;
                    bf16x8 vb = *reinterpret_cast<const bf16x8*>(
                        (const char*)Vs[cur] + ((row * 128 + (ks * 4 + lhi) * 16) ^ ((row & 7) << 4)));
                    oacc[0][nf] = __builtin_amdgcn_mfma_f32_16x16x32_bf16(pa0, vb, oacc[0][nf], 0, 0, 0);
                    oacc[1][nf] = __builtin_amdgcn_mfma_f32_16x16x32_bf16(pa1, vb, oacc[1][nf], 0, 0, 0);
                }
            }

            asm volatile("s_waitcnt vmcnt(0)" ::: "memory");
            __builtin_amdgcn_s_barrier();
        }

        // ---- final L reduce + epilogue ----
#pragma unroll
        for (int m = 1; m < 16; m <<= 1)
#pragma unroll
            for (int mf = 0; mf < 2; ++mf)
#pragma unroll
                for (int r = 0; r < 4; ++r)
                    Lp[mf][r] += __shfl_xor(Lp[mf][r], m);
#pragma unroll
        for (int mf = 0; mf < 2; ++mf) {
            float inv[4];
#pragma unroll
            for (int r = 0; r < 4; ++r) inv[r] = 1.f / Lp[mf][r];
#pragma unroll
            for (int nf = 0; nf < 8; ++nf)
#pragma unroll
                for (int r = 0; r < 4; ++r) {
                    int s = qw0 + mf * 16 + lhi * 4 + r;
                    int d = nf * 16 + l15;
                    Ob[((size_t)(b * SS + s)) * HH + h * HD + d] = (bf16)(oacc[mf][nf][r] * inv[r]);
                }
        }
    }
}

// ---------------------------------------------------------------------------
extern "C" void kernel_launch(void* const* d_in, const int* in_sizes, int n_in,
                              void* d_out, int out_size, void* d_ws, size_t ws_size,
                              hipStream_t stream) {
    const float* hs   = (const float*)d_in[0];
    const float* cosT = (const float*)d_in[2];
    const float* sinT = (const float*)d_in[3];
    const float* Wq   = (const float*)d_in[4];
    const float* Wk   = (const float*)d_in[5];
    const float* Wv   = (const float*)d_in[6];
    const float* Wo   = (const float*)d_in[7];
    float* out = (float*)d_out;

    char* w = (char*)d_ws;
    auto alloc = [&](size_t bytes) {
        char* p = w;
        w += (bytes + 255) & ~(size_t)255;
        return p;
    };
    const size_t XE = (size_t)BB * SS * HH;
    const size_t WE = (size_t)HH * HH;
    bf16* Xb   = (bf16*)alloc(XE * 2);
    bf16* Wqkv = (bf16*)alloc(3 * WE * 2);
    bf16* Wob  = (bf16*)alloc(WE * 2);
    bf16* QKV  = (bf16*)alloc(3 * XE * 2);
    bf16* Vtg  = (bf16*)alloc(XE * 2);
    bf16* Ob   = (bf16*)alloc(XE * 2);

    const int M = BB * SS;  // 4096
    bf16* Qh = QKV;
    bf16* Kh = QKV + XE;
    bf16* Vh = QKV + 2 * XE;

    {
        int total4 = (int)((XE + 4 * WE) / 4);
        cast_all<<<(total4 + 255) / 256, 256, 0, stream>>>(hs, Wq, Wk, Wv, Wo, Xb, Wqkv, Wob);
    }

    // fused QKV projection: 256x192 tiles, 512 blocks (R12)
    gemm256_qkv<<<512, 512, 0, stream>>>(Xb, Wqkv, QKV, M, 3 * HH, HH);

    // merged RoPE (Q,K) + V transpose
    rope_tv<<<4096, 256, 0, stream>>>(Qh, Kh, cosT, sinT, Vh, Vtg);

    // attention v2: 256 blocks x 256 threads (4 waves x 32 rows)
    attn_kernel<<<256, 256, 0, stream>>>(Qh, Kh, Vtg, Ob);

    // out projection: 256x128 tiles, 256 blocks = 1 round
    gemm_op<<<256, 512, 0, stream>>>(Ob, Wob, out, M, HH, HH);
}

// Round 14
// 261.296 us; speedup vs baseline: 1.0486x; 1.0486x over previous
//
#include <hip/hip_runtime.h>
#include <hip/hip_bf16.h>

typedef __bf16 bf16;
typedef __attribute__((ext_vector_type(8))) __bf16 bf16x8;
typedef __attribute__((ext_vector_type(4))) __bf16 bf16x4;
typedef __attribute__((ext_vector_type(4))) float f32x4;

// Problem constants
#define BB 2
#define SS 2048
#define HH 2048
#define NH 16
#define HD 128

#define GLOAD_LDS16(g, l)                                                  \
    __builtin_amdgcn_global_load_lds(                                      \
        (const __attribute__((address_space(1))) void*)(g),                \
        (__attribute__((address_space(3))) void*)(l), 16, 0, 0)

// ---------------------------------------------------------------------------
// Batched fp32 -> bf16 cast: X then Wq,Wk,Wv (into contiguous Wqkv), Wo.
// ---------------------------------------------------------------------------
__global__ __launch_bounds__(256) void cast_all(const float* __restrict__ hs,
                                                const float* __restrict__ Wq,
                                                const float* __restrict__ Wk,
                                                const float* __restrict__ Wv,
                                                const float* __restrict__ Wo,
                                                bf16* __restrict__ Xb,
                                                bf16* __restrict__ Wqkv,
                                                bf16* __restrict__ Wob) {
    const int XE4 = (BB * SS * HH) / 4;
    const int WE4 = (HH * HH) / 4;
    int i = blockIdx.x * 256 + threadIdx.x;
    const float* src;
    bf16* dst;
    int off;
    if (i < XE4) { src = hs; dst = Xb; off = i; }
    else if (i < XE4 + WE4) { src = Wq; dst = Wqkv; off = i - XE4; }
    else if (i < XE4 + 2 * WE4) { src = Wk; dst = Wqkv + (size_t)HH * HH; off = i - XE4 - WE4; }
    else if (i < XE4 + 3 * WE4) { src = Wv; dst = Wqkv + 2 * (size_t)HH * HH; off = i - XE4 - 2 * WE4; }
    else { src = Wo; dst = Wob; off = i - XE4 - 3 * WE4; }
    f32x4 v = *reinterpret_cast<const f32x4*>(src + (size_t)off * 4);
    bf16x4 o;
    o[0] = (bf16)v[0]; o[1] = (bf16)v[1]; o[2] = (bf16)v[2]; o[3] = (bf16)v[3];
    *reinterpret_cast<bf16x4*>(dst + (size_t)off * 4) = o;
}

// ---------------------------------------------------------------------------
// 256x192-tile 3-phase GEMM, QKV epilogue. Grid 16m x 32n = 512 blocks =
// exactly 2 rounds on 256 CUs. 8 waves (2m x 4n); per-wave 128x48 =
// acc[8][3]. BK=64, double-buffered. 3-bit both-sides swizzle. Staging:
// p0->B2(t+1), p1->B0+A0(t+2), p2->B1+A1(t+2); boundary vmcnt(6).
// ---------------------------------------------------------------------------
__global__ __launch_bounds__(512, 2) void gemm256_qkv(const bf16* __restrict__ A,
                                                      const bf16* __restrict__ B,
                                                      bf16* __restrict__ Cb,
                                                      int M, int N, int K) {
    __shared__ bf16 LA[2][256 * 64];
    __shared__ bf16 LB[2][192 * 64];
    const int tid = threadIdx.x, lane = tid & 63, wave = tid >> 6;
    const int l15 = lane & 15, lhi = lane >> 4;
    const int wr = wave >> 2, wc = wave & 3;
    const int cpx = gridDim.x >> 3;
    const int wg = (blockIdx.x & 7) * cpx + (blockIdx.x >> 3);
    const int m0 = (wg & 15) * 256, n0 = (wg >> 4) * 192;
    const int NK = K >> 6;
    const int xorR = (l15 & 7) << 4;

    auto stageA = [&](int buf, int t, int h) {
        const int k0 = t << 6;
#pragma unroll
        for (int j = 0; j < 2; ++j) {
            int Xw = (h * 128 + j * 64 + wave * 8) << 7;
            int X = Xw + lane * 16;
            int T = X ^ (((X >> 7) & 7) << 4);
            GLOAD_LDS16(&A[(size_t)(m0 + (T >> 7)) * K + k0 + ((T & 127) >> 1)],
                        (char*)LA[buf] + Xw);
        }
    };
    auto stageB = [&](int buf, int t, int s) {
        const int k0 = t << 6;
        int row_base = (wave >> 1) * 48 + s * 16 + (wave & 1) * 8;
        int Xw = row_base << 7;
        int X = Xw + lane * 16;
        int T = X ^ (((X >> 7) & 7) << 4);
        GLOAD_LDS16(&B[(size_t)(n0 + (T >> 7)) * K + k0 + ((T & 127) >> 1)],
                    (char*)LB[buf] + Xw);
    };

    f32x4 acc[8][3] = {};

    stageA(0, 0, 0); stageA(0, 0, 1);
    stageB(0, 0, 0); stageB(0, 0, 1); stageB(0, 0, 2);
    stageA(1, 1, 0); stageA(1, 1, 1);
    stageB(1, 1, 0); stageB(1, 1, 1);
    asm volatile("s_waitcnt vmcnt(6)" ::: "memory");
    __builtin_amdgcn_s_barrier();

    bf16x8 af[8][2], bv[2];

#pragma unroll 1
    for (int t = 0; t < NK; ++t) {
        const int buf = t & 1;
        char* lA = (char*)LA[buf];
        char* lB = (char*)LB[buf];

        // p0: af(16) + bv s0(2); stage B2(t+1)
#pragma unroll
        for (int mf = 0; mf < 8; ++mf)
#pragma unroll
            for (int ks = 0; ks < 2; ++ks) {
                int T = ((wr * 128 + mf * 16 + l15) << 7) + ks * 64 + lhi * 16;
                af[mf][ks] = *reinterpret_cast<const bf16x8*>(lA + (T ^ xorR));
            }
#pragma unroll
        for (int ks = 0; ks < 2; ++ks) {
            int T = ((wc * 48 + l15) << 7) + ks * 64 + lhi * 16;
            bv[ks] = *reinterpret_cast<const bf16x8*>(lB + (T ^ xorR));
        }
        if (t + 1 < NK) stageB(buf ^ 1, t + 1, 2);
        __builtin_amdgcn_s_barrier();
        __builtin_amdgcn_s_setprio(1);
#pragma unroll
        for (int mf = 0; mf < 8; ++mf)
#pragma unroll
            for (int ks = 0; ks < 2; ++ks)
                acc[mf][0] = __builtin_amdgcn_mfma_f32_16x16x32_bf16(af[mf][ks], bv[ks], acc[mf][0], 0, 0, 0);
        __builtin_amdgcn_s_setprio(0);
        __builtin_amdgcn_s_barrier();

        // p1: bv s1(2); stage B0+A0(t+2)
#pragma unroll
        for (int ks = 0; ks < 2; ++ks) {
            int T = ((wc * 48 + 16 + l15) << 7) + ks * 64 + lhi * 16;
            bv[ks] = *reinterpret_cast<const bf16x8*>(lB + (T ^ xorR));
        }
        if (t + 2 < NK) { stageB(buf, t + 2, 0); stageA(buf, t + 2, 0); }
        __builtin_amdgcn_s_barrier();
        __builtin_amdgcn_s_setprio(1);
#pragma unroll
        for (int mf = 0; mf < 8; ++mf)
#pragma unroll
            for (int ks = 0; ks < 2; ++ks)
                acc[mf][1] = __builtin_amdgcn_mfma_f32_16x16x32_bf16(af[mf][ks], bv[ks], acc[mf][1], 0, 0, 0);
        __builtin_amdgcn_s_setprio(0);
        __builtin_amdgcn_s_barrier();

        // p2: bv s2(2); stage B1+A1(t+2); boundary vmcnt
#pragma unroll
        for (int ks = 0; ks < 2; ++ks) {
            int T = ((wc * 48 + 32 + l15) << 7) + ks * 64 + lhi * 16;
            bv[ks] = *reinterpret_cast<const bf16x8*>(lB + (T ^ xorR));
        }
        if (t + 2 < NK) { stageB(buf, t + 2, 1); stageA(buf, t + 2, 1); }
        __builtin_amdgcn_s_barrier();
        __builtin_amdgcn_s_setprio(1);
#pragma unroll
        for (int mf = 0; mf < 8; ++mf)
#pragma unroll
            for (int ks = 0; ks < 2; ++ks)
                acc[mf][2] = __builtin_amdgcn_mfma_f32_16x16x32_bf16(af[mf][ks], bv[ks], acc[mf][2], 0, 0, 0);
        __builtin_amdgcn_s_setprio(0);
        if (t + 2 < NK) {
            asm volatile("s_waitcnt vmcnt(6)" ::: "memory");
        } else if (t + 2 == NK) {
            asm volatile("s_waitcnt vmcnt(0)" ::: "memory");
        }
        __builtin_amdgcn_s_barrier();
    }

#pragma unroll
    for (int mf = 0; mf < 8; ++mf)
#pragma unroll
        for (int nsl = 0; nsl < 3; ++nsl)
#pragma unroll
            for (int r = 0; r < 4; ++r) {
                int gm = m0 + wr * 128 + mf * 16 + lhi * 4 + r;
                int gn = n0 + wc * 48 + nsl * 16 + l15;
                int proj = gn >> 11, n2 = gn & 2047;
                int b = gm >> 11, s = gm & (SS - 1);
                int h = n2 >> 7, d = n2 & (HD - 1);
                Cb[((size_t)proj << 23) + ((((size_t)(b * NH + h)) * SS + s) << 7) + d] =
                    (bf16)acc[mf][nsl][r];
            }
}

// ---------------------------------------------------------------------------
// 128x128 GEMM (m97 structure), fp32 epilogue (out projection), 2D grid.
// ---------------------------------------------------------------------------
__global__ __launch_bounds__(256) void gemm_bt(const bf16* __restrict__ A,
                                               const bf16* __restrict__ B,
                                               float* __restrict__ Cf,
                                               int M, int N, int K) {
    __shared__ bf16 As[128 * 64];
    __shared__ bf16 Bs[128 * 64];
    const int tid = threadIdx.x;
    const int lane = tid & 63, wave = tid >> 6;
    const int l15 = lane & 15, lhi = lane >> 4;
    const int m0 = blockIdx.y * 128, n0 = blockIdx.x * 128;
    const int wm = (wave >> 1) * 64, wn = (wave & 1) * 64;
    const int lrow = lane >> 3;
    const int lcol = (lane & 7) * 8;

    f32x4 acc[4][4] = {};

    for (int k0 = 0; k0 < K; k0 += 64) {
#pragma unroll
        for (int j = 0; j < 4; ++j) {
            const int c = wave * 4 + j;
            const int row = c * 8 + lrow;
            GLOAD_LDS16(&A[(size_t)(m0 + row) * K + k0 + lcol], &As[c * 512]);
            GLOAD_LDS16(&B[(size_t)(n0 + row) * K + k0 + lcol], &Bs[c * 512]);
        }
        __syncthreads();
#pragma unroll
        for (int ks = 0; ks < 2; ++ks) {
            bf16x8 af[4], bfr[4];
#pragma unroll
            for (int i = 0; i < 4; ++i)
                af[i] = *reinterpret_cast<const bf16x8*>(&As[(wm + i * 16 + l15) * 64 + ks * 32 + 8 * lhi]);
#pragma unroll
            for (int j = 0; j < 4; ++j)
                bfr[j] = *reinterpret_cast<const bf16x8*>(&Bs[(wn + j * 16 + l15) * 64 + ks * 32 + 8 * lhi]);
#pragma unroll
            for (int i = 0; i < 4; ++i)
#pragma unroll
                for (int j = 0; j < 4; ++j)
                    acc[i][j] = __builtin_amdgcn_mfma_f32_16x16x32_bf16(af[i], bfr[j], acc[i][j], 0, 0, 0);
        }
        __syncthreads();
    }

#pragma unroll
    for (int i = 0; i < 4; ++i)
#pragma unroll
        for (int j = 0; j < 4; ++j)
#pragma unroll
            for (int r = 0; r < 4; ++r) {
                int gm = m0 + wm + i * 16 + lhi * 4 + r;
                int gn = n0 + wn + j * 16 + l15;
                Cf[(size_t)gm * N + gn] = acc[i][j][r];
            }
}

// ---------------------------------------------------------------------------
// Merged RoPE + V-transpose (one launch, two block ranges).
// ---------------------------------------------------------------------------
__global__ __launch_bounds__(256) void rope_tv(bf16* __restrict__ Qh,
                                               bf16* __restrict__ Kh,
                                               const float* __restrict__ cosT,
                                               const float* __restrict__ sinT,
                                               const bf16* __restrict__ Vh,
                                               bf16* __restrict__ Vt) {
    __shared__ bf16 T[64 * 64];
    const int tid = threadIdx.x;
    if (blockIdx.x < 2048) {
        int idx = blockIdx.x * 256 + tid;
        int g = idx & 7;
        int s = (idx >> 3) & (SS - 1);
        int head = idx >> 14;
        int d0 = g * 8;
        size_t base = ((size_t)head * SS + s) * HD;
        f32x4 ca = *reinterpret_cast<const f32x4*>(&cosT[s * HD + d0]);
        f32x4 cb = *reinterpret_cast<const f32x4*>(&cosT[s * HD + d0 + 4]);
        f32x4 sa = *reinterpret_cast<const f32x4*>(&sinT[s * HD + d0]);
        f32x4 sb = *reinterpret_cast<const f32x4*>(&sinT[s * HD + d0 + 4]);
        bf16x8 ql = *reinterpret_cast<const bf16x8*>(&Qh[base + d0]);
        bf16x8 qh = *reinterpret_cast<const bf16x8*>(&Qh[base + 64 + d0]);
        bf16x8 kl = *reinterpret_cast<const bf16x8*>(&Kh[base + d0]);
        bf16x8 kh = *reinterpret_cast<const bf16x8*>(&Kh[base + 64 + d0]);
        bf16x8 qlo, qhi, klo, khi;
#pragma unroll
        for (int j = 0; j < 8; ++j) {
            float c = (j < 4) ? ca[j] : cb[j - 4];
            float sn = (j < 4) ? sa[j] : sb[j - 4];
            float q0 = (float)ql[j], q1 = (float)qh[j];
            float k0 = (float)kl[j], k1 = (float)kh[j];
            qlo[j] = (bf16)(q0 * c - q1 * sn);
            qhi[j] = (bf16)(q1 * c + q0 * sn);
            klo[j] = (bf16)(k0 * c - k1 * sn);
            khi[j] = (bf16)(k1 * c + k0 * sn);
        }
        *reinterpret_cast<bf16x8*>(&Qh[base + d0]) = qlo;
        *reinterpret_cast<bf16x8*>(&Qh[base + 64 + d0]) = qhi;
        *reinterpret_cast<bf16x8*>(&Kh[base + d0]) = klo;
        *reinterpret_cast<bf16x8*>(&Kh[base + 64 + d0]) = khi;
    } else {
        const int b2 = blockIdx.x - 2048;
        const int s0 = (b2 & 31) * 64;
        const int d0 = ((b2 >> 5) & 1) * 64;
        const int head = b2 >> 6;
        const bf16* src = Vh + ((size_t)head * SS) * HD;
        bf16* dst = Vt + ((size_t)head * HD) * SS;

#pragma unroll
        for (int i = 0; i < 2; ++i) {
            int id = tid + i * 256;
            int r = id >> 3, c16 = id & 7;
            bf16x8 v = *reinterpret_cast<const bf16x8*>(&src[(size_t)(s0 + r) * HD + d0 + c16 * 8]);
            int sw = c16 ^ ((r ^ (r >> 3)) & 7);
            *reinterpret_cast<bf16x8*>((char*)T + r * 128 + sw * 16) = v;
        }
        __syncthreads();
#pragma unroll
        for (int i = 0; i < 2; ++i) {
            int id = tid + i * 256;
            int dr = id >> 3, sc8 = (id & 7) * 8;
            bf16x8 o;
#pragma unroll
            for (int j = 0; j < 8; ++j) {
                int r = sc8 + j;
                int sw = (dr >> 3) ^ ((r ^ (r >> 3)) & 7);
                o[j] = *reinterpret_cast<const bf16*>((char*)T + r * 128 + sw * 16 + (dr & 7) * 2);
            }
            *reinterpret_cast<bf16x8*>(&dst[(size_t)(d0 + dr) * SS + s0 + sc8]) = o;
        }
    }
}

// ---------------------------------------------------------------------------
// Causal flash attention (R10 proven version): QB=128, 8 waves x 16 q-rows,
// KVBLK=64, K/V dbuf via global_load_lds, one barrier/iter, uniform pairs.
// Grid 256 = 32 heads x 8 pairs (T, 15-T): uniform 34 iters/block.
// ---------------------------------------------------------------------------
__global__ __launch_bounds__(512) void attn_kernel(const bf16* __restrict__ Q,
                                                   const bf16* __restrict__ K,
                                                   const bf16* __restrict__ Vt,
                                                   bf16* __restrict__ Ob) {
    __shared__ bf16 Ks[2][64 * 128];
    __shared__ bf16 Vs[2][128 * 64];
    __shared__ bf16 Ps[8][16 * 72];

    const int tid = threadIdx.x, lane = tid & 63, wave = tid >> 6;
    const int l15 = lane & 15, lhi = lane >> 4;
    const int bid = blockIdx.x;
    const int orig = (bid & 7) * 32 + (bid >> 3);   // XCD swizzle (256 % 8 == 0)
    const int head = orig >> 3;
    const int pi = orig & 7;
    const int b = head >> 4, h = head & (NH - 1);
    const size_t hb = (size_t)head * SS * HD;
    const bf16* Vth = Vt + (size_t)head * HD * SS;
    const float cexp = 0.08838834764831845f * 1.4426950408889634f;
    const float THR = 62.0f;

    auto stageKV = [&](int buf, int kv0) {
#pragma unroll
        for (int j = 0; j < 2; ++j) {
            int Xw = (j * 8 + wave) << 10;
            int X = Xw + lane * 16;
            int T = X ^ (((X >> 8) & 7) << 4);
            GLOAD_LDS16(&K[hb + (size_t)(kv0 + (T >> 8)) * HD + ((T & 255) >> 1)],
                        (char*)Ks[buf] + Xw);
        }
#pragma unroll
        for (int j = 0; j < 2; ++j) {
            int Xw = (j * 8 + wave) << 10;
            int X = Xw + lane * 16;
            int T = X ^ (((X >> 7) & 7) << 4);
            GLOAD_LDS16(&Vth[(size_t)(T >> 7) * SS + kv0 + ((T & 127) >> 1)],
                        (char*)Vs[buf] + Xw);
        }
    };

#pragma unroll 1
    for (int part = 0; part < 2; ++part) {
        const int t = part ? (15 - pi) : pi;
        const int q0 = t * 128;
        const int qw = q0 + wave * 16;
        const int nkv = 2 * t + 2;

        bf16x8 qf[4];
#pragma unroll
        for (int ks = 0; ks < 4; ++ks)
            qf[ks] = *reinterpret_cast<const bf16x8*>(
                &Q[hb + (size_t)(qw + l15) * HD + ks * 32 + 8 * lhi]);

        f32x4 oacc[8] = {};
        float Mr[4], Lp[4];
#pragma unroll
        for (int r = 0; r < 4; ++r) { Mr[r] = -INFINITY; Lp[r] = 0.f; }

        stageKV(0, 0);
        asm volatile("s_waitcnt vmcnt(0)" ::: "memory");
        __builtin_amdgcn_s_barrier();

        for (int it = 0; it < nkv; ++it) {
            const int cur = it & 1;
            if (it + 1 < nkv) stageKV(cur ^ 1, (it + 1) * 64);

            f32x4 sf[4] = {};
#pragma unroll
            for (int ks = 0; ks < 4; ++ks) {
#pragma unroll
                for (int ne = 0; ne < 4; ++ne) {
                    int row = ne * 16 + l15;
                    bf16x8 kf = *reinterpret_cast<const bf16x8*>(
                        (const char*)Ks[cur] + ((row * 256 + (ks * 4 + lhi) * 16) ^ ((row & 7) << 4)));
                    sf[ne] = __builtin_amdgcn_mfma_f32_16x16x32_bf16(qf[ks], kf, sf[ne], 0, 0, 0);
                }
            }

            if (it >= nkv - 2) {
#pragma unroll
                for (int ne = 0; ne < 4; ++ne)
#pragma unroll
                    for (int r = 0; r < 4; ++r) {
                        int gq = qw + lhi * 4 + r;
                        int gk = it * 64 + ne * 16 + l15;
                        if (gk > gq) sf[ne][r] = -INFINITY;
                    }
            }

            float lm[4];
#pragma unroll
            for (int r = 0; r < 4; ++r)
                lm[r] = fmaxf(fmaxf(sf[0][r], sf[1][r]), fmaxf(sf[2][r], sf[3][r]));
            bool need = (lm[0] > Mr[0] + THR) || (lm[1] > Mr[1] + THR) ||
                        (lm[2] > Mr[2] + THR) || (lm[3] > Mr[3] + THR);
            if (__any(need)) {
                float rmax[4] = {lm[0], lm[1], lm[2], lm[3]};
#pragma unroll
                for (int m = 1; m < 16; m <<= 1)
#pragma unroll
                    for (int r = 0; r < 4; ++r)
                        rmax[r] = fmaxf(rmax[r], __shfl_xor(rmax[r], m));
#pragma unroll
                for (int r = 0; r < 4; ++r) {
                    float nM = fmaxf(Mr[r], rmax[r]);
                    float scf = __builtin_amdgcn_exp2f((Mr[r] - nM) * cexp);
                    Mr[r] = nM;
                    Lp[r] *= scf;
#pragma unroll
                    for (int nf = 0; nf < 8; ++nf) oacc[nf][r] *= scf;
                }
            }
#pragma unroll
            for (int ne = 0; ne < 4; ++ne)
#pragma unroll
                for (int r = 0; r < 4; ++r) {
                    float p = __builtin_amdgcn_exp2f((sf[ne][r] - Mr[r]) * cexp);
                    Lp[r] += p;
                    Ps[wave][(lhi * 4 + r) * 72 + ne * 16 + l15] = (bf16)p;
                }

#pragma unroll
            for (int ks = 0; ks < 2; ++ks) {
                bf16x8 pa = *reinterpret_cast<const bf16x8*>(
                    &Ps[wave][l15 * 72 + ks * 32 + 8 * lhi]);
#pragma unroll
                for (int nf = 0; nf < 8; ++nf) {
                    int row = nf * 16 + l15;
                    bf16x8 vb = *reinterpret_cast<const bf16x8*>(
                        (const char*)Vs[cur] + ((row * 128 + (ks * 4 + lhi) * 16) ^ ((row & 7) << 4)));
                    oacc[nf] = __builtin_amdgcn_mfma_f32_16x16x32_bf16(pa, vb, oacc[nf], 0, 0, 0);
                }
            }

            asm volatile("s_waitcnt vmcnt(0)" ::: "memory");
            __builtin_amdgcn_s_barrier();
        }

#pragma unroll
        for (int m = 1; m < 16; m <<= 1)
#pragma unroll
            for (int r = 0; r < 4; ++r)
                Lp[r] += __shfl_xor(Lp[r], m);
        float inv[4];
#pragma unroll
        for (int r = 0; r < 4; ++r) inv[r] = 1.f / Lp[r];
#pragma unroll
        for (int nf = 0; nf < 8; ++nf)
#pragma unroll
            for (int r = 0; r < 4; ++r) {
                int s = qw + lhi * 4 + r;
                int d = nf * 16 + l15;
                Ob[((size_t)(b * SS + s)) * HH + h * HD + d] = (bf16)(oacc[nf][r] * inv[r]);
            }
    }
}

// ---------------------------------------------------------------------------
extern "C" void kernel_launch(void* const* d_in, const int* in_sizes, int n_in,
                              void* d_out, int out_size, void* d_ws, size_t ws_size,
                              hipStream_t stream) {
    const float* hs   = (const float*)d_in[0];
    const float* cosT = (const float*)d_in[2];
    const float* sinT = (const float*)d_in[3];
    const float* Wq   = (const float*)d_in[4];
    const float* Wk   = (const float*)d_in[5];
    const float* Wv   = (const float*)d_in[6];
    const float* Wo   = (const float*)d_in[7];
    float* out = (float*)d_out;

    char* w = (char*)d_ws;
    auto alloc = [&](size_t bytes) {
        char* p = w;
        w += (bytes + 255) & ~(size_t)255;
        return p;
    };
    const size_t XE = (size_t)BB * SS * HH;
    const size_t WE = (size_t)HH * HH;
    bf16* Xb   = (bf16*)alloc(XE * 2);
    bf16* Wqkv = (bf16*)alloc(3 * WE * 2);
    bf16* Wob  = (bf16*)alloc(WE * 2);
    bf16* QKV  = (bf16*)alloc(3 * XE * 2);
    bf16* Vtg  = (bf16*)alloc(XE * 2);
    bf16* Ob   = (bf16*)alloc(XE * 2);

    const int M = BB * SS;  // 4096
    bf16* Qh = QKV;
    bf16* Kh = QKV + XE;
    bf16* Vh = QKV + 2 * XE;

    {
        int total4 = (int)((XE + 4 * WE) / 4);
        cast_all<<<(total4 + 255) / 256, 256, 0, stream>>>(hs, Wq, Wk, Wv, Wo, Xb, Wqkv, Wob);
    }

    // fused QKV projection: 256x192 tiles, 512 blocks (R12)
    gemm256_qkv<<<512, 512, 0, stream>>>(Xb, Wqkv, QKV, M, 3 * HH, HH);

    // merged RoPE (Q,K) + V transpose
    rope_tv<<<4096, 256, 0, stream>>>(Qh, Kh, cosT, sinT, Vh, Vtg);

    // attention: 256 blocks x 512 threads (R10)
    attn_kernel<<<256, 512, 0, stream>>>(Qh, Kh, Vtg, Ob);

    // out projection: 128x128 2D grid (R12)
    dim3 ogrid(HH / 128, M / 128);
    gemm_bt<<<ogrid, 256, 0, stream>>>(Ob, Wob, out, M, HH, HH);
}

// Round 15
// 257.088 us; speedup vs baseline: 1.0658x; 1.0164x over previous
//
#include <hip/hip_runtime.h>
#include <hip/hip_bf16.h>

typedef __bf16 bf16;
typedef __attribute__((ext_vector_type(8))) __bf16 bf16x8;
typedef __attribute__((ext_vector_type(4))) __bf16 bf16x4;
typedef __attribute__((ext_vector_type(4))) float f32x4;

// Problem constants
#define BB 2
#define SS 2048
#define HH 2048
#define NH 16
#define HD 128

#define GLOAD_LDS16(g, l)                                                  \
    __builtin_amdgcn_global_load_lds(                                      \
        (const __attribute__((address_space(1))) void*)(g),                \
        (__attribute__((address_space(3))) void*)(l), 16, 0, 0)

// ---------------------------------------------------------------------------
// Batched fp32 -> bf16 cast: X then Wq,Wk,Wv (into contiguous Wqkv), Wo.
// ---------------------------------------------------------------------------
__global__ __launch_bounds__(256) void cast_all(const float* __restrict__ hs,
                                                const float* __restrict__ Wq,
                                                const float* __restrict__ Wk,
                                                const float* __restrict__ Wv,
                                                const float* __restrict__ Wo,
                                                bf16* __restrict__ Xb,
                                                bf16* __restrict__ Wqkv,
                                                bf16* __restrict__ Wob) {
    const int XE4 = (BB * SS * HH) / 4;
    const int WE4 = (HH * HH) / 4;
    int i = blockIdx.x * 256 + threadIdx.x;
    const float* src;
    bf16* dst;
    int off;
    if (i < XE4) { src = hs; dst = Xb; off = i; }
    else if (i < XE4 + WE4) { src = Wq; dst = Wqkv; off = i - XE4; }
    else if (i < XE4 + 2 * WE4) { src = Wk; dst = Wqkv + (size_t)HH * HH; off = i - XE4 - WE4; }
    else if (i < XE4 + 3 * WE4) { src = Wv; dst = Wqkv + 2 * (size_t)HH * HH; off = i - XE4 - 2 * WE4; }
    else { src = Wo; dst = Wob; off = i - XE4 - 3 * WE4; }
    f32x4 v = *reinterpret_cast<const f32x4*>(src + (size_t)off * 4);
    bf16x4 o;
    o[0] = (bf16)v[0]; o[1] = (bf16)v[1]; o[2] = (bf16)v[2]; o[3] = (bf16)v[3];
    *reinterpret_cast<bf16x4*>(dst + (size_t)off * 4) = o;
}

// ---------------------------------------------------------------------------
// 256x192-tile 3-phase GEMM, QKV epilogue (R12 proven, 120 us).
// ---------------------------------------------------------------------------
__global__ __launch_bounds__(512, 2) void gemm256_qkv(const bf16* __restrict__ A,
                                                      const bf16* __restrict__ B,
                                                      bf16* __restrict__ Cb,
                                                      int M, int N, int K) {
    __shared__ bf16 LA[2][256 * 64];
    __shared__ bf16 LB[2][192 * 64];
    const int tid = threadIdx.x, lane = tid & 63, wave = tid >> 6;
    const int l15 = lane & 15, lhi = lane >> 4;
    const int wr = wave >> 2, wc = wave & 3;
    const int cpx = gridDim.x >> 3;
    const int wg = (blockIdx.x & 7) * cpx + (blockIdx.x >> 3);
    const int m0 = (wg & 15) * 256, n0 = (wg >> 4) * 192;
    const int NK = K >> 6;
    const int xorR = (l15 & 7) << 4;

    auto stageA = [&](int buf, int t, int h) {
        const int k0 = t << 6;
#pragma unroll
        for (int j = 0; j < 2; ++j) {
            int Xw = (h * 128 + j * 64 + wave * 8) << 7;
            int X = Xw + lane * 16;
            int T = X ^ (((X >> 7) & 7) << 4);
            GLOAD_LDS16(&A[(size_t)(m0 + (T >> 7)) * K + k0 + ((T & 127) >> 1)],
                        (char*)LA[buf] + Xw);
        }
    };
    auto stageB = [&](int buf, int t, int s) {
        const int k0 = t << 6;
        int row_base = (wave >> 1) * 48 + s * 16 + (wave & 1) * 8;
        int Xw = row_base << 7;
        int X = Xw + lane * 16;
        int T = X ^ (((X >> 7) & 7) << 4);
        GLOAD_LDS16(&B[(size_t)(n0 + (T >> 7)) * K + k0 + ((T & 127) >> 1)],
                    (char*)LB[buf] + Xw);
    };

    f32x4 acc[8][3] = {};

    stageA(0, 0, 0); stageA(0, 0, 1);
    stageB(0, 0, 0); stageB(0, 0, 1); stageB(0, 0, 2);
    stageA(1, 1, 0); stageA(1, 1, 1);
    stageB(1, 1, 0); stageB(1, 1, 1);
    asm volatile("s_waitcnt vmcnt(6)" ::: "memory");
    __builtin_amdgcn_s_barrier();

    bf16x8 af[8][2], bv[2];

#pragma unroll 1
    for (int t = 0; t < NK; ++t) {
        const int buf = t & 1;
        char* lA = (char*)LA[buf];
        char* lB = (char*)LB[buf];

        // p0: af(16) + bv s0(2); stage B2(t+1)
#pragma unroll
        for (int mf = 0; mf < 8; ++mf)
#pragma unroll
            for (int ks = 0; ks < 2; ++ks) {
                int T = ((wr * 128 + mf * 16 + l15) << 7) + ks * 64 + lhi * 16;
                af[mf][ks] = *reinterpret_cast<const bf16x8*>(lA + (T ^ xorR));
            }
#pragma unroll
        for (int ks = 0; ks < 2; ++ks) {
            int T = ((wc * 48 + l15) << 7) + ks * 64 + lhi * 16;
            bv[ks] = *reinterpret_cast<const bf16x8*>(lB + (T ^ xorR));
        }
        if (t + 1 < NK) stageB(buf ^ 1, t + 1, 2);
        __builtin_amdgcn_s_barrier();
        __builtin_amdgcn_s_setprio(1);
#pragma unroll
        for (int mf = 0; mf < 8; ++mf)
#pragma unroll
            for (int ks = 0; ks < 2; ++ks)
                acc[mf][0] = __builtin_amdgcn_mfma_f32_16x16x32_bf16(af[mf][ks], bv[ks], acc[mf][0], 0, 0, 0);
        __builtin_amdgcn_s_setprio(0);
        __builtin_amdgcn_s_barrier();

        // p1: bv s1(2); stage B0+A0(t+2)
#pragma unroll
        for (int ks = 0; ks < 2; ++ks) {
            int T = ((wc * 48 + 16 + l15) << 7) + ks * 64 + lhi * 16;
            bv[ks] = *reinterpret_cast<const bf16x8*>(lB + (T ^ xorR));
        }
        if (t + 2 < NK) { stageB(buf, t + 2, 0); stageA(buf, t + 2, 0); }
        __builtin_amdgcn_s_barrier();
        __builtin_amdgcn_s_setprio(1);
#pragma unroll
        for (int mf = 0; mf < 8; ++mf)
#pragma unroll
            for (int ks = 0; ks < 2; ++ks)
                acc[mf][1] = __builtin_amdgcn_mfma_f32_16x16x32_bf16(af[mf][ks], bv[ks], acc[mf][1], 0, 0, 0);
        __builtin_amdgcn_s_setprio(0);
        __builtin_amdgcn_s_barrier();

        // p2: bv s2(2); stage B1+A1(t+2); boundary vmcnt
#pragma unroll
        for (int ks = 0; ks < 2; ++ks) {
            int T = ((wc * 48 + 32 + l15) << 7) + ks * 64 + lhi * 16;
            bv[ks] = *reinterpret_cast<const bf16x8*>(lB + (T ^ xorR));
        }
        if (t + 2 < NK) { stageB(buf, t + 2, 1); stageA(buf, t + 2, 1); }
        __builtin_amdgcn_s_barrier();
        __builtin_amdgcn_s_setprio(1);
#pragma unroll
        for (int mf = 0; mf < 8; ++mf)
#pragma unroll
            for (int ks = 0; ks < 2; ++ks)
                acc[mf][2] = __builtin_amdgcn_mfma_f32_16x16x32_bf16(af[mf][ks], bv[ks], acc[mf][2], 0, 0, 0);
        __builtin_amdgcn_s_setprio(0);
        if (t + 2 < NK) {
            asm volatile("s_waitcnt vmcnt(6)" ::: "memory");
        } else if (t + 2 == NK) {
            asm volatile("s_waitcnt vmcnt(0)" ::: "memory");
        }
        __builtin_amdgcn_s_barrier();
    }

#pragma unroll
    for (int mf = 0; mf < 8; ++mf)
#pragma unroll
        for (int nsl = 0; nsl < 3; ++nsl)
#pragma unroll
            for (int r = 0; r < 4; ++r) {
                int gm = m0 + wr * 128 + mf * 16 + lhi * 4 + r;
                int gn = n0 + wc * 48 + nsl * 16 + l15;
                int proj = gn >> 11, n2 = gn & 2047;
                int b = gm >> 11, s = gm & (SS - 1);
                int h = n2 >> 7, d = n2 & (HD - 1);
                Cb[((size_t)proj << 23) + ((((size_t)(b * NH + h)) * SS + s) << 7) + d] =
                    (bf16)acc[mf][nsl][r];
            }
}

// ---------------------------------------------------------------------------
// Out-projection: 256x128-tile 2-phase GEMM, fp32 epilogue.
// Grid 16m x 16n = 256 blocks = exactly 1 round. 8 waves (2x4); per-wave
// 128x32 = acc[8][2]. Staging: p0->Bs1(t+1), p1->Bs0+A0+A1(t+2);
// boundary vmcnt(5). n-major XCD chunks. (Correctness verified in R13.)
// ---------------------------------------------------------------------------
__global__ __launch_bounds__(512, 2) void gemm_op(const bf16* __restrict__ A,
                                                  const bf16* __restrict__ B,
                                                  float* __restrict__ Cf,
                                                  int M, int N, int K) {
    __shared__ bf16 LA[2][256 * 64];   // 64 KiB
    __shared__ bf16 LB[2][128 * 64];   // 32 KiB
    const int tid = threadIdx.x, lane = tid & 63, wave = tid >> 6;
    const int l15 = lane & 15, lhi = lane >> 4;
    const int wr = wave >> 2, wc = wave & 3;
    const int cpx = gridDim.x >> 3;                        // 32
    const int wg = (blockIdx.x & 7) * cpx + (blockIdx.x >> 3);
    const int m0 = (wg & 15) * 256, n0 = (wg >> 4) * 128;  // n-major chunks
    const int NK = K >> 6;
    const int xorR = (l15 & 7) << 4;

    auto stageA = [&](int buf, int t, int h) {
        const int k0 = t << 6;
#pragma unroll
        for (int j = 0; j < 2; ++j) {
            int Xw = (h * 128 + j * 64 + wave * 8) << 7;
            int X = Xw + lane * 16;
            int T = X ^ (((X >> 7) & 7) << 4);
            GLOAD_LDS16(&A[(size_t)(m0 + (T >> 7)) * K + k0 + ((T & 127) >> 1)],
                        (char*)LA[buf] + Xw);
        }
    };
    auto stageB = [&](int buf, int t, int s) {
        const int k0 = t << 6;
        int row_base = (wave >> 1) * 32 + s * 16 + (wave & 1) * 8;
        int Xw = row_base << 7;
        int X = Xw + lane * 16;
        int T = X ^ (((X >> 7) & 7) << 4);
        GLOAD_LDS16(&B[(size_t)(n0 + (T >> 7)) * K + k0 + ((T & 127) >> 1)],
                    (char*)LB[buf] + Xw);
    };

    f32x4 acc[8][2] = {};

    stageA(0, 0, 0); stageA(0, 0, 1); stageB(0, 0, 0); stageB(0, 0, 1);
    stageA(1, 1, 0); stageA(1, 1, 1); stageB(1, 1, 0);
    asm volatile("s_waitcnt vmcnt(5)" ::: "memory");
    __builtin_amdgcn_s_barrier();

    bf16x8 af[8][2], bv[2];

#pragma unroll 1
    for (int t = 0; t < NK; ++t) {
        const int buf = t & 1;
        char* lA = (char*)LA[buf];
        char* lB = (char*)LB[buf];

        // p0: af(16) + bv s0(2); stage Bs1(t+1)
#pragma unroll
        for (int mf = 0; mf < 8; ++mf)
#pragma unroll
            for (int ks = 0; ks < 2; ++ks) {
                int T = ((wr * 128 + mf * 16 + l15) << 7) + ks * 64 + lhi * 16;
                af[mf][ks] = *reinterpret_cast<const bf16x8*>(lA + (T ^ xorR));
            }
#pragma unroll
        for (int ks = 0; ks < 2; ++ks) {
            int T = ((wc * 32 + l15) << 7) + ks * 64 + lhi * 16;
            bv[ks] = *reinterpret_cast<const bf16x8*>(lB + (T ^ xorR));
        }
        if (t + 1 < NK) stageB(buf ^ 1, t + 1, 1);
        __builtin_amdgcn_s_barrier();
        __builtin_amdgcn_s_setprio(1);
#pragma unroll
        for (int mf = 0; mf < 8; ++mf)
#pragma unroll
            for (int ks = 0; ks < 2; ++ks)
                acc[mf][0] = __builtin_amdgcn_mfma_f32_16x16x32_bf16(af[mf][ks], bv[ks], acc[mf][0], 0, 0, 0);
        __builtin_amdgcn_s_setprio(0);
        __builtin_amdgcn_s_barrier();

        // p1: bv s1(2); stage Bs0+A0+A1(t+2); boundary vmcnt(5)
#pragma unroll
        for (int ks = 0; ks < 2; ++ks) {
            int T = ((wc * 32 + 16 + l15) << 7) + ks * 64 + lhi * 16;
            bv[ks] = *reinterpret_cast<const bf16x8*>(lB + (T ^ xorR));
        }
        if (t + 2 < NK) { stageB(buf, t + 2, 0); stageA(buf, t + 2, 0); stageA(buf, t + 2, 1); }
        __builtin_amdgcn_s_barrier();
        __builtin_amdgcn_s_setprio(1);
#pragma unroll
        for (int mf = 0; mf < 8; ++mf)
#pragma unroll
            for (int ks = 0; ks < 2; ++ks)
                acc[mf][1] = __builtin_amdgcn_mfma_f32_16x16x32_bf16(af[mf][ks], bv[ks], acc[mf][1], 0, 0, 0);
        __builtin_amdgcn_s_setprio(0);
        if (t + 2 < NK) {
            asm volatile("s_waitcnt vmcnt(5)" ::: "memory");
        } else {
            asm volatile("s_waitcnt vmcnt(0)" ::: "memory");
        }
        __builtin_amdgcn_s_barrier();
    }

#pragma unroll
    for (int mf = 0; mf < 8; ++mf)
#pragma unroll
        for (int nsl = 0; nsl < 2; ++nsl)
#pragma unroll
            for (int r = 0; r < 4; ++r) {
                int gm = m0 + wr * 128 + mf * 16 + lhi * 4 + r;
                int gn = n0 + wc * 32 + nsl * 16 + l15;
                Cf[(size_t)gm * N + gn] = acc[mf][nsl][r];
            }
}

// ---------------------------------------------------------------------------
// Merged RoPE + V-transpose (one launch, two block ranges).
// ---------------------------------------------------------------------------
__global__ __launch_bounds__(256) void rope_tv(bf16* __restrict__ Qh,
                                               bf16* __restrict__ Kh,
                                               const float* __restrict__ cosT,
                                               const float* __restrict__ sinT,
                                               const bf16* __restrict__ Vh,
                                               bf16* __restrict__ Vt) {
    __shared__ bf16 T[64 * 64];
    const int tid = threadIdx.x;
    if (blockIdx.x < 2048) {
        int idx = blockIdx.x * 256 + tid;
        int g = idx & 7;
        int s = (idx >> 3) & (SS - 1);
        int head = idx >> 14;
        int d0 = g * 8;
        size_t base = ((size_t)head * SS + s) * HD;
        f32x4 ca = *reinterpret_cast<const f32x4*>(&cosT[s * HD + d0]);
        f32x4 cb = *reinterpret_cast<const f32x4*>(&cosT[s * HD + d0 + 4]);
        f32x4 sa = *reinterpret_cast<const f32x4*>(&sinT[s * HD + d0]);
        f32x4 sb = *reinterpret_cast<const f32x4*>(&sinT[s * HD + d0 + 4]);
        bf16x8 ql = *reinterpret_cast<const bf16x8*>(&Qh[base + d0]);
        bf16x8 qh = *reinterpret_cast<const bf16x8*>(&Qh[base + 64 + d0]);
        bf16x8 kl = *reinterpret_cast<const bf16x8*>(&Kh[base + d0]);
        bf16x8 kh = *reinterpret_cast<const bf16x8*>(&Kh[base + 64 + d0]);
        bf16x8 qlo, qhi, klo, khi;
#pragma unroll
        for (int j = 0; j < 8; ++j) {
            float c = (j < 4) ? ca[j] : cb[j - 4];
            float sn = (j < 4) ? sa[j] : sb[j - 4];
            float q0 = (float)ql[j], q1 = (float)qh[j];
            float k0 = (float)kl[j], k1 = (float)kh[j];
            qlo[j] = (bf16)(q0 * c - q1 * sn);
            qhi[j] = (bf16)(q1 * c + q0 * sn);
            klo[j] = (bf16)(k0 * c - k1 * sn);
            khi[j] = (bf16)(k1 * c + k0 * sn);
        }
        *reinterpret_cast<bf16x8*>(&Qh[base + d0]) = qlo;
        *reinterpret_cast<bf16x8*>(&Qh[base + 64 + d0]) = qhi;
        *reinterpret_cast<bf16x8*>(&Kh[base + d0]) = klo;
        *reinterpret_cast<bf16x8*>(&Kh[base + 64 + d0]) = khi;
    } else {
        const int b2 = blockIdx.x - 2048;
        const int s0 = (b2 & 31) * 64;
        const int d0 = ((b2 >> 5) & 1) * 64;
        const int head = b2 >> 6;
        const bf16* src = Vh + ((size_t)head * SS) * HD;
        bf16* dst = Vt + ((size_t)head * HD) * SS;

#pragma unroll
        for (int i = 0; i < 2; ++i) {
            int id = tid + i * 256;
            int r = id >> 3, c16 = id & 7;
            bf16x8 v = *reinterpret_cast<const bf16x8*>(&src[(size_t)(s0 + r) * HD + d0 + c16 * 8]);
            int sw = c16 ^ ((r ^ (r >> 3)) & 7);
            *reinterpret_cast<bf16x8*>((char*)T + r * 128 + sw * 16) = v;
        }
        __syncthreads();
#pragma unroll
        for (int i = 0; i < 2; ++i) {
            int id = tid + i * 256;
            int dr = id >> 3, sc8 = (id & 7) * 8;
            bf16x8 o;
#pragma unroll
            for (int j = 0; j < 8; ++j) {
                int r = sc8 + j;
                int sw = (dr >> 3) ^ ((r ^ (r >> 3)) & 7);
                o[j] = *reinterpret_cast<const bf16*>((char*)T + r * 128 + sw * 16 + (dr & 7) * 2);
            }
            *reinterpret_cast<bf16x8*>(&dst[(size_t)(d0 + dr) * SS + s0 + sc8]) = o;
        }
    }
}

// ---------------------------------------------------------------------------
// Causal flash attention (R10 proven version): QB=128, 8 waves x 16 q-rows,
// KVBLK=64, K/V dbuf via global_load_lds, one barrier/iter, uniform pairs.
// Grid 256 = 32 heads x 8 pairs (T, 15-T): uniform 34 iters/block.
// ---------------------------------------------------------------------------
__global__ __launch_bounds__(512) void attn_kernel(const bf16* __restrict__ Q,
                                                   const bf16* __restrict__ K,
                                                   const bf16* __restrict__ Vt,
                                                   bf16* __restrict__ Ob) {
    __shared__ bf16 Ks[2][64 * 128];
    __shared__ bf16 Vs[2][128 * 64];
    __shared__ bf16 Ps[8][16 * 72];

    const int tid = threadIdx.x, lane = tid & 63, wave = tid >> 6;
    const int l15 = lane & 15, lhi = lane >> 4;
    const int bid = blockIdx.x;
    const int orig = (bid & 7) * 32 + (bid >> 3);   // XCD swizzle (256 % 8 == 0)
    const int head = orig >> 3;
    const int pi = orig & 7;
    const int b = head >> 4, h = head & (NH - 1);
    const size_t hb = (size_t)head * SS * HD;
    const bf16* Vth = Vt + (size_t)head * HD * SS;
    const float cexp = 0.08838834764831845f * 1.4426950408889634f;
    const float THR = 62.0f;

    auto stageKV = [&](int buf, int kv0) {
#pragma unroll
        for (int j = 0; j < 2; ++j) {
            int Xw = (j * 8 + wave) << 10;
            int X = Xw + lane * 16;
            int T = X ^ (((X >> 8) & 7) << 4);
            GLOAD_LDS16(&K[hb + (size_t)(kv0 + (T >> 8)) * HD + ((T & 255) >> 1)],
                        (char*)Ks[buf] + Xw);
        }
#pragma unroll
        for (int j = 0; j < 2; ++j) {
            int Xw = (j * 8 + wave) << 10;
            int X = Xw + lane * 16;
            int T = X ^ (((X >> 7) & 7) << 4);
            GLOAD_LDS16(&Vth[(size_t)(T >> 7) * SS + kv0 + ((T & 127) >> 1)],
                        (char*)Vs[buf] + Xw);
        }
    };

#pragma unroll 1
    for (int part = 0; part < 2; ++part) {
        const int t = part ? (15 - pi) : pi;
        const int q0 = t * 128;
        const int qw = q0 + wave * 16;
        const int nkv = 2 * t + 2;

        bf16x8 qf[4];
#pragma unroll
        for (int ks = 0; ks < 4; ++ks)
            qf[ks] = *reinterpret_cast<const bf16x8*>(
                &Q[hb + (size_t)(qw + l15) * HD + ks * 32 + 8 * lhi]);

        f32x4 oacc[8] = {};
        float Mr[4], Lp[4];
#pragma unroll
        for (int r = 0; r < 4; ++r) { Mr[r] = -INFINITY; Lp[r] = 0.f; }

        stageKV(0, 0);
        asm volatile("s_waitcnt vmcnt(0)" ::: "memory");
        __builtin_amdgcn_s_barrier();

        for (int it = 0; it < nkv; ++it) {
            const int cur = it & 1;
            if (it + 1 < nkv) stageKV(cur ^ 1, (it + 1) * 64);

            f32x4 sf[4] = {};
#pragma unroll
            for (int ks = 0; ks < 4; ++ks) {
#pragma unroll
                for (int ne = 0; ne < 4; ++ne) {
                    int row = ne * 16 + l15;
                    bf16x8 kf = *reinterpret_cast<const bf16x8*>(
                        (const char*)Ks[cur] + ((row * 256 + (ks * 4 + lhi) * 16) ^ ((row & 7) << 4)));
                    sf[ne] = __builtin_amdgcn_mfma_f32_16x16x32_bf16(qf[ks], kf, sf[ne], 0, 0, 0);
                }
            }

            if (it >= nkv - 2) {
#pragma unroll
                for (int ne = 0; ne < 4; ++ne)
#pragma unroll
                    for (int r = 0; r < 4; ++r) {
                        int gq = qw + lhi * 4 + r;
                        int gk = it * 64 + ne * 16 + l15;
                        if (gk > gq) sf[ne][r] = -INFINITY;
                    }
            }

            float lm[4];
#pragma unroll
            for (int r = 0; r < 4; ++r)
                lm[r] = fmaxf(fmaxf(sf[0][r], sf[1][r]), fmaxf(sf[2][r], sf[3][r]));
            bool need = (lm[0] > Mr[0] + THR) || (lm[1] > Mr[1] + THR) ||
                        (lm[2] > Mr[2] + THR) || (lm[3] > Mr[3] + THR);
            if (__any(need)) {
                float rmax[4] = {lm[0], lm[1], lm[2], lm[3]};
#pragma unroll
                for (int m = 1; m < 16; m <<= 1)
#pragma unroll
                    for (int r = 0; r < 4; ++r)
                        rmax[r] = fmaxf(rmax[r], __shfl_xor(rmax[r], m));
#pragma unroll
                for (int r = 0; r < 4; ++r) {
                    float nM = fmaxf(Mr[r], rmax[r]);
                    float scf = __builtin_amdgcn_exp2f((Mr[r] - nM) * cexp);
                    Mr[r] = nM;
                    Lp[r] *= scf;
#pragma unroll
                    for (int nf = 0; nf < 8; ++nf) oacc[nf][r] *= scf;
                }
            }
#pragma unroll
            for (int ne = 0; ne < 4; ++ne)
#pragma unroll
                for (int r = 0; r < 4; ++r) {
                    float p = __builtin_amdgcn_exp2f((sf[ne][r] - Mr[r]) * cexp);
                    Lp[r] += p;
                    Ps[wave][(lhi * 4 + r) * 72 + ne * 16 + l15] = (bf16)p;
                }

#pragma unroll
            for (int ks = 0; ks < 2; ++ks) {
                bf16x8 pa = *reinterpret_cast<const bf16x8*>(
                    &Ps[wave][l15 * 72 + ks * 32 + 8 * lhi]);
#pragma unroll
                for (int nf = 0; nf < 8; ++nf) {
                    int row = nf * 16 + l15;
                    bf16x8 vb = *reinterpret_cast<const bf16x8*>(
                        (const char*)Vs[cur] + ((row * 128 + (ks * 4 + lhi) * 16) ^ ((row & 7) << 4)));
                    oacc[nf] = __builtin_amdgcn_mfma_f32_16x16x32_bf16(pa, vb, oacc[nf], 0, 0, 0);
                }
            }

            asm volatile("s_waitcnt vmcnt(0)" ::: "memory");
            __builtin_amdgcn_s_barrier();
        }

#pragma unroll
        for (int m = 1; m < 16; m <<= 1)
#pragma unroll
            for (int r = 0; r < 4; ++r)
                Lp[r] += __shfl_xor(Lp[r], m);
        float inv[4];
#pragma unroll
        for (int r = 0; r < 4; ++r) inv[r] = 1.f / Lp[r];
#pragma unroll
        for (int nf = 0; nf < 8; ++nf)
#pragma unroll
            for (int r = 0; r < 4; ++r) {
                int s = qw + lhi * 4 + r;
                int d = nf * 16 + l15;
                Ob[((size_t)(b * SS + s)) * HH + h * HD + d] = (bf16)(oacc[nf][r] * inv[r]);
            }
    }
}

// ---------------------------------------------------------------------------
extern "C" void kernel_launch(void* const* d_in, const int* in_sizes, int n_in,
                              void* d_out, int out_size, void* d_ws, size_t ws_size,
                              hipStream_t stream) {
    const float* hs   = (const float*)d_in[0];
    const float* cosT = (const float*)d_in[2];
    const float* sinT = (const float*)d_in[3];
    const float* Wq   = (const float*)d_in[4];
    const float* Wk   = (const float*)d_in[5];
    const float* Wv   = (const float*)d_in[6];
    const float* Wo   = (const float*)d_in[7];
    float* out = (float*)d_out;

    char* w = (char*)d_ws;
    auto alloc = [&](size_t bytes) {
        char* p = w;
        w += (bytes + 255) & ~(size_t)255;
        return p;
    };
    const size_t XE = (size_t)BB * SS * HH;
    const size_t WE = (size_t)HH * HH;
    bf16* Xb   = (bf16*)alloc(XE * 2);
    bf16* Wqkv = (bf16*)alloc(3 * WE * 2);
    bf16* Wob  = (bf16*)alloc(WE * 2);
    bf16* QKV  = (bf16*)alloc(3 * XE * 2);
    bf16* Vtg  = (bf16*)alloc(XE * 2);
    bf16* Ob   = (bf16*)alloc(XE * 2);

    const int M = BB * SS;  // 4096
    bf16* Qh = QKV;
    bf16* Kh = QKV + XE;
    bf16* Vh = QKV + 2 * XE;

    {
        int total4 = (int)((XE + 4 * WE) / 4);
        cast_all<<<(total4 + 255) / 256, 256, 0, stream>>>(hs, Wq, Wk, Wv, Wo, Xb, Wqkv, Wob);
    }

    // fused QKV projection: 256x192 tiles, 512 blocks (R12)
    gemm256_qkv<<<512, 512, 0, stream>>>(Xb, Wqkv, QKV, M, 3 * HH, HH);

    // merged RoPE (Q,K) + V transpose
    rope_tv<<<4096, 256, 0, stream>>>(Qh, Kh, cosT, sinT, Vh, Vtg);

    // attention: 256 blocks x 512 threads (R10)
    attn_kernel<<<256, 512, 0, stream>>>(Qh, Kh, Vtg, Ob);

    // out projection: 256x128 tiles, 256 blocks = 1 round (isolated test)
    gemm_op<<<256, 512, 0, stream>>>(Ob, Wob, out, M, HH, HH);
}